// Round 2
// baseline (948.037 us; speedup 1.0000x reference)
//
#include <hip/hip_runtime.h>
#include <hip/hip_fp16.h>

// ---------------- workspace layout (float offsets) ----------------
constexpr size_t OFF_Y0   = 0;         // 8*16*128*128 = 2097152
constexpr size_t OFF_Y1   = 2097152;   // 8*32*64*64   = 1048576
constexpr size_t OFF_Y2   = 3145728;   // 8*64*32*32   = 524288
constexpr size_t OFF_Y3   = 3670016;   // 8*128*16*16  = 262144
constexpr size_t OFF_SS0  = 3932160;   // 8*16*2
constexpr size_t OFF_SS1  = 3932416;   // 8*32*2
constexpr size_t OFF_SS2  = 3932928;   // 8*64*2
constexpr size_t OFF_SS3  = 3933952;   // 8*128*2
constexpr size_t OFF_FEAT = 3936000;   // 8*128
constexpr size_t OFF_WGT  = 3937024;   // 8*20 (padded)
constexpr size_t OFF_T    = 3937280;   // 300*1089 = 326700
constexpr size_t OFF_LUT4 = 4264064;   // 8*35937 entries * 16B (fp16 r-pairs)
// STAT buffers overlap dead regions (zeroed just-in-time):
//  STAT0/1/2 live in Y3's head (Y3 written only by conv3, after finalize2)
//  STAT3 lives in Y0's head (Y0 dead after conv1; zeroed inside finalize1)
constexpr size_t OFF_STAT0 = OFF_Y3;        // 8*16*2  = 256
constexpr size_t OFF_STAT1 = OFF_Y3 + 256;  // 8*32*2  = 512
constexpr size_t OFF_STAT2 = OFF_Y3 + 768;  // 8*64*2  = 1024
constexpr size_t OFF_STAT3 = OFF_Y0;        // 8*128*2 = 2048

__global__ __launch_bounds__(256) void zero_k(float* __restrict__ p, int n) {
  int i = blockIdx.x*256 + threadIdx.x;
  if (i < n) p[i] = 0.f;
}

// ---------------- conv stride-2 3x3 + lrelu, stats via atomics ----------------
// 1D grid: lin = b + 8*(oc + COUT*split)  ->  lin%8==b pins batch b to XCD b.
template<int CIN, int COUT, int HIN, int WIN, int BLK, int SPLIT, bool FIRST>
__global__ __launch_bounds__(BLK) void conv_s2(
    const float* __restrict__ xin, const float* __restrict__ wgt,
    const float* __restrict__ bias, const float* __restrict__ ss_in,
    float* __restrict__ yout, float* __restrict__ stat)
{
  constexpr int HOUT = HIN/2, WOUT = WIN/2, NPX = HOUT*WOUT;
  constexpr int NSTRIP = NPX/4, SPW = WOUT/4, CH = NSTRIP/SPLIT;
  constexpr int LOG2C = __builtin_ctz(COUT);
  const int lin = blockIdx.x;
  const int b = lin & 7;
  const int rest = lin >> 3;
  const int oc = rest & (COUT-1);
  const int split = rest >> LOG2C;

  __shared__ float sw[CIN*9];
  __shared__ float sh[CIN*9];
  __shared__ float s_shsum;
  __shared__ float rbuf[2][BLK/64];

  if (threadIdx.x == 0) s_shsum = 0.f;
  for (int i = threadIdx.x; i < CIN*9; i += BLK) {
    int ic = i/9;
    float sc, sf;
    if constexpr (FIRST) {
      const float mv[3] = {0.485f, 0.456f, 0.406f};
      const float sv[3] = {0.229f, 0.224f, 0.225f};
      sc = 1.f/sv[ic]; sf = -mv[ic]/sv[ic];
    } else {
      sc = ss_in[(b*CIN+ic)*2+0]; sf = ss_in[(b*CIN+ic)*2+1];
    }
    float w = wgt[oc*CIN*9 + i];
    sw[i] = w*sc; sh[i] = w*sf;
  }
  __syncthreads();
  {
    float part = 0.f;
    for (int i = threadIdx.x; i < CIN*9; i += BLK) part += sh[i];
    #pragma unroll
    for (int off = 32; off; off >>= 1) part += __shfl_down(part, off);
    if ((threadIdx.x & 63) == 0) atomicAdd(&s_shsum, part);
  }
  __syncthreads();
  const float shsum = s_shsum;
  const float bb = bias[oc];
  const float* xb = xin + (size_t)b*CIN*HIN*WIN;
  float* yp = yout + ((size_t)b*COUT + oc)*NPX;
  float lsum = 0.f, lsq = 0.f;

  const int s0 = split*CH;
  for (int s = s0 + threadIdx.x; s < s0 + CH; s += BLK) {
    int oy = s / SPW, sx = s - oy*SPW, ox0 = sx*4;
    float acc[4];
    if (oy > 0 && ox0 > 0) {
      #pragma unroll
      for (int j = 0; j < 4; ++j) acc[j] = bb + shsum;
      const float* x0 = xb + (oy*2-1)*WIN + (ox0*2-1);
      for (int ic = 0; ic < CIN; ++ic) {
        const float* xp = x0 + ic*HIN*WIN;
        const float* wp = &sw[ic*9];
        #pragma unroll
        for (int ky = 0; ky < 3; ++ky) {
          const float* row = xp + ky*WIN;
          float xv[9];
          #pragma unroll
          for (int t = 0; t < 9; ++t) xv[t] = row[t];
          float w0 = wp[ky*3], w1 = wp[ky*3+1], w2 = wp[ky*3+2];
          acc[0] += w0*xv[0] + w1*xv[1] + w2*xv[2];
          acc[1] += w0*xv[2] + w1*xv[3] + w2*xv[4];
          acc[2] += w0*xv[4] + w1*xv[5] + w2*xv[6];
          acc[3] += w0*xv[6] + w1*xv[7] + w2*xv[8];
        }
      }
    } else {
      #pragma unroll
      for (int j = 0; j < 4; ++j) acc[j] = bb;
      for (int ic = 0; ic < CIN; ++ic) {
        const float* xp = xb + ic*HIN*WIN;
        const float* wp = &sw[ic*9];
        const float* hp = &sh[ic*9];
        #pragma unroll
        for (int ky = 0; ky < 3; ++ky) {
          int iy = oy*2-1+ky;
          if (iy < 0) continue;
          const float* row = xp + iy*WIN;
          #pragma unroll
          for (int kx = 0; kx < 3; ++kx) {
            float w = wp[ky*3+kx], hh = hp[ky*3+kx];
            #pragma unroll
            for (int j = 0; j < 4; ++j) {
              int ix = (ox0+j)*2-1+kx;
              if (ix >= 0) acc[j] += w*row[ix] + hh;
            }
          }
        }
      }
    }
    float4 o;
    float* op = (float*)&o;
    #pragma unroll
    for (int j = 0; j < 4; ++j) {
      float a = acc[j];
      a = a >= 0.f ? a : 0.2f*a;       // lrelu
      op[j] = a;
      lsum += a; lsq += a*a;
    }
    *(float4*)(yp + oy*WOUT + ox0) = o;
  }

  // block-reduce stats -> atomic partial into stat[(b*COUT+oc)*2]
  #pragma unroll
  for (int off = 32; off; off >>= 1) {
    lsum += __shfl_down(lsum, off);
    lsq  += __shfl_down(lsq,  off);
  }
  int wid = threadIdx.x >> 6;
  if ((threadIdx.x & 63) == 0) { rbuf[0][wid] = lsum; rbuf[1][wid] = lsq; }
  __syncthreads();
  if (threadIdx.x == 0) {
    float S = 0.f, Q = 0.f;
    #pragma unroll
    for (int w = 0; w < BLK/64; ++w) { S += rbuf[0][w]; Q += rbuf[1][w]; }
    atomicAdd(&stat[(b*COUT+oc)*2+0], S);
    atomicAdd(&stat[(b*COUT+oc)*2+1], Q);
  }
}

// ---------------- finalize: stat -> scale/shift (+ optional zeroing of next stat buf) --------
template<int COUT, int NPX>
__global__ __launch_bounds__(256) void finalize_k(
    const float* __restrict__ stat, const float* __restrict__ g, const float* __restrict__ be,
    float* __restrict__ ss, float* __restrict__ zp, int zero_n)
{
  int i = blockIdx.x*256 + threadIdx.x;
  if (i < 8*COUT) {
    float S = stat[2*i], Q = stat[2*i+1];
    float mean = S*(1.0f/NPX);
    float var  = Q*(1.0f/NPX) - mean*mean;
    float rstd = rsqrtf(var + 1e-5f);
    int ocl = i & (COUT-1);
    float gg = g[ocl], bb = be[ocl];
    ss[2*i+0] = gg*rstd;
    ss[2*i+1] = bb - mean*gg*rstd;
  }
  for (int z = i; z < zero_n; z += gridDim.x*256) zp[z] = 0.f;
}

// ---------------- last conv (128->128, 16x16 -> 8x8) + lrelu + global mean -> feat ----------
__global__ __launch_bounds__(64) void conv_s2_last(
    const float* __restrict__ xin, const float* __restrict__ wgt,
    const float* __restrict__ bias, const float* __restrict__ ss_in,
    float* __restrict__ feat)
{
  constexpr int CIN = 128;
  const int lin = blockIdx.x;
  const int b = lin & 7, oc = lin >> 3;
  __shared__ float sw[CIN*9];
  __shared__ float sh[CIN*9];
  __shared__ float s_shsum;
  for (int i = threadIdx.x; i < CIN*9; i += 64) {
    int ic = i/9;
    float sc = ss_in[(b*CIN+ic)*2+0], sf = ss_in[(b*CIN+ic)*2+1];
    float w = wgt[oc*CIN*9 + i];
    sw[i] = w*sc; sh[i] = w*sf;
  }
  __syncthreads();
  float part = 0.f;
  for (int i = threadIdx.x; i < CIN*9; i += 64) part += sh[i];
  #pragma unroll
  for (int off = 32; off; off >>= 1) part += __shfl_down(part, off);
  if (threadIdx.x == 0) s_shsum = part;
  __syncthreads();

  const int p = threadIdx.x;       // 64 px = 8x8
  const int oy = p >> 3, ox = p & 7;
  const float* xb = xin + (size_t)b*CIN*256;
  float acc;
  if (oy > 0 && ox > 0) {
    acc = bias[oc] + s_shsum;
    const float* x0 = xb + (oy*2-1)*16 + (ox*2-1);
    for (int ic = 0; ic < CIN; ++ic) {
      const float* xp = x0 + ic*256;
      const float* wp = &sw[ic*9];
      #pragma unroll
      for (int ky = 0; ky < 3; ++ky) {
        const float* row = xp + ky*16;
        acc += wp[ky*3]*row[0] + wp[ky*3+1]*row[1] + wp[ky*3+2]*row[2];
      }
    }
  } else {
    acc = bias[oc];
    for (int ic = 0; ic < CIN; ++ic) {
      const float* wp = &sw[ic*9];
      const float* hp = &sh[ic*9];
      #pragma unroll
      for (int ky = 0; ky < 3; ++ky) {
        int iy = oy*2-1+ky;
        if (iy < 0) continue;
        #pragma unroll
        for (int kx = 0; kx < 3; ++kx) {
          int ix = ox*2-1+kx;
          if (ix >= 0) acc += wp[ky*3+kx]*xb[ic*256 + iy*16 + ix] + hp[ky*3+kx];
        }
      }
    }
  }
  acc = acc >= 0.f ? acc : 0.2f*acc;
  float s = acc;
  #pragma unroll
  for (int off = 32; off; off >>= 1) s += __shfl_down(s, off);
  if (threadIdx.x == 0) feat[b*128 + oc] = s * (1.0f/64.0f);
}

// ---------------- classifier head ----------------
__global__ __launch_bounds__(256) void head_kernel(
    const float* __restrict__ feat, const float* __restrict__ w0, const float* __restrict__ b0,
    const float* __restrict__ w1, const float* __restrict__ b1, float* __restrict__ wout)
{
  __shared__ float sh_h[8*128];
  const int tid = threadIdx.x;
  for (int i = tid; i < 8*128; i += 256) {
    int b = i >> 7, t = i & 127;
    const float* f = feat + b*128;
    const float* w = w0 + t*128;
    float a = b0[t];
    for (int k = 0; k < 128; ++k) a += f[k]*w[k];
    float c = fminf(fmaxf(a + 3.f, 0.f), 6.f);
    sh_h[i] = a * c * (1.f/6.f);            // hardswish
  }
  __syncthreads();
  for (int i = tid; i < 8*20; i += 256) {
    int b = i/20, n = i - b*20;
    const float* h = sh_h + b*128;
    const float* w = w1 + n*128;
    float a = b1[n];
    for (int k = 0; k < 128; ++k) a += h[k]*w[k];
    wout[b*20 + n] = a;
  }
}

// ---------------- T = luts(300x20) @ w_layers(20x1089) ----------------
__global__ __launch_bounds__(256) void tmat_kernel(
    const float* __restrict__ luts, const float* __restrict__ wl, float* __restrict__ T)
{
  int q = blockIdx.x*256 + threadIdx.x;
  int row = blockIdx.y;
  if (q >= 1089) return;
  float a = 0.f;
  #pragma unroll
  for (int w = 0; w < 20; ++w) a += luts[row*20 + w] * wl[w*1089 + q];
  T[row*1089 + q] = a;
}

// ---------------- per-batch 3D LUT, fp16 r-corner pairs, 16B per (b,g,r) entry -------------
// entry i=(bi,gi,ri): halves {r(ri),g(ri),b(ri),pad, r(ri+1),g(ri+1),b(ri+1),pad}
// ch0: d0=r, q=bi*33+gi (q indep of r -> share inner sums)
// ch1: d0=gi, q=bi*33+r | ch2: d0=bi, q=gi*33+r
__global__ __launch_bounds__(256) void lut_kernel(
    const float* __restrict__ T, const float* __restrict__ wgt,
    const float* __restrict__ slay, float4* __restrict__ lut)
{
  const int lin = blockIdx.x;
  const int bt = lin & 7;
  const int i = (lin >> 3)*256 + threadIdx.x;
  if (i >= 35937) return;
  int bi = i / 1089, rem = i - bi*1089, gi = rem / 33, ri = rem - gi*33;
  int r1 = ri < 32 ? ri + 1 : 32;
  float w[20];
  #pragma unroll
  for (int n = 0; n < 20; ++n) w[n] = wgt[bt*20 + n];

  float ch0_a = 0.f, ch0_b = 0.f;
  {
    int q = bi*33 + gi;
    #pragma unroll
    for (int s = 0; s < 5; ++s) {
      float t = 0.f;
      #pragma unroll
      for (int n = 0; n < 20; ++n) t += w[n] * T[(s*60 + n*3 + 0)*1089 + q];
      ch0_a += slay[ri*5 + s]*t;
      ch0_b += slay[r1*5 + s]*t;
    }
  }
  float ch1_v[2], ch2_v[2];
  #pragma unroll
  for (int k = 0; k < 2; ++k) {
    int rr = k ? r1 : ri;
    float v1 = 0.f, v2 = 0.f;
    #pragma unroll
    for (int s = 0; s < 5; ++s) {
      float t1 = 0.f, t2 = 0.f;
      #pragma unroll
      for (int n = 0; n < 20; ++n) {
        t1 += w[n] * T[(s*60 + n*3 + 1)*1089 + bi*33 + rr];
        t2 += w[n] * T[(s*60 + n*3 + 2)*1089 + gi*33 + rr];
      }
      v1 += slay[gi*5 + s]*t1;
      v2 += slay[bi*5 + s]*t2;
    }
    ch1_v[k] = v1; ch2_v[k] = v2;
  }
  union { float4 f4; __half h[8]; } u;
  u.h[0] = __float2half(ch0_a); u.h[1] = __float2half(ch1_v[0]);
  u.h[2] = __float2half(ch2_v[0]); u.h[3] = __half(0.f);
  u.h[4] = __float2half(ch0_b); u.h[5] = __float2half(ch1_v[1]);
  u.h[6] = __float2half(ch2_v[1]); u.h[7] = __half(0.f);
  lut[(size_t)bt*35937 + i] = u.f4;
}

// ---------------- trilinear apply + residual (4 gathers/px) ----------------
__global__ __launch_bounds__(256) void trilin_kernel(
    const float* __restrict__ img, const float4* __restrict__ lut, float* __restrict__ out)
{
  constexpr int NPX = 720*1280, NV = NPX/4;
  const int lin = blockIdx.x;
  const int bt = lin & 7;
  const int v = (lin >> 3)*256 + threadIdx.x;   // < NV exactly (900*256)
  const float* ib = img + (size_t)bt*3*NPX;
  float4 r4 = *((const float4*)ib + v);
  float4 g4 = *((const float4*)(ib + NPX) + v);
  float4 b4 = *((const float4*)(ib + 2*NPX) + v);
  const float4* L = lut + (size_t)bt*35937;
  const float invbin = 32.0f/1.000001f;
  float4 ro, go, bo;
  float* rp = (float*)&ro; float* gp = (float*)&go; float* bp = (float*)&bo;
  #pragma unroll
  for (int j = 0; j < 4; ++j) {
    float r = ((float*)&r4)[j], g = ((float*)&g4)[j], b = ((float*)&b4)[j];
    float pr = r*invbin, pg = g*invbin, pb = b*invbin;
    int ri = (int)pr; ri = ri > 31 ? 31 : ri; ri = ri < 0 ? 0 : ri;
    int gi = (int)pg; gi = gi > 31 ? 31 : gi; gi = gi < 0 ? 0 : gi;
    int bi = (int)pb; bi = bi > 31 ? 31 : bi; bi = bi < 0 ? 0 : bi;
    float fr = pr - ri, fg = pg - gi, fb = pb - bi;
    int base = (bi*33 + gi)*33 + ri;
    float4 q00 = L[base];        // (g0,b0)
    float4 q10 = L[base+33];     // (g1,b0)
    float4 q01 = L[base+1089];   // (g0,b1)
    float4 q11 = L[base+1122];   // (g1,b1)
    const __half2* h00 = (const __half2*)&q00;
    const __half2* h10 = (const __half2*)&q10;
    const __half2* h01 = (const __half2*)&q01;
    const __half2* h11 = (const __half2*)&q11;
    float2 a00 = __half22float2(h00[0]), e00 = __half22float2(h00[1]);
    float2 c00 = __half22float2(h00[2]), d00 = __half22float2(h00[3]);
    float2 a10 = __half22float2(h10[0]), e10 = __half22float2(h10[1]);
    float2 c10 = __half22float2(h10[2]), d10 = __half22float2(h10[3]);
    float2 a01 = __half22float2(h01[0]), e01 = __half22float2(h01[1]);
    float2 c01 = __half22float2(h01[2]), d01 = __half22float2(h01[3]);
    float2 a11 = __half22float2(h11[0]), e11 = __half22float2(h11[1]);
    float2 c11 = __half22float2(h11[2]), d11 = __half22float2(h11[3]);
    // lerp over r inside each pair: val = lo + fr*(hi-lo)
    float cr00 = a00.x + fr*(c00.x - a00.x), cg00 = a00.y + fr*(c00.y - a00.y), cb00 = e00.x + fr*(d00.x - e00.x);
    float cr10 = a10.x + fr*(c10.x - a10.x), cg10 = a10.y + fr*(c10.y - a10.y), cb10 = e10.x + fr*(d10.x - e10.x);
    float cr01 = a01.x + fr*(c01.x - a01.x), cg01 = a01.y + fr*(c01.y - a01.y), cb01 = e01.x + fr*(d01.x - e01.x);
    float cr11 = a11.x + fr*(c11.x - a11.x), cg11 = a11.y + fr*(c11.y - a11.y), cb11 = e11.x + fr*(d11.x - e11.x);
    float w00 = (1.f-fg)*(1.f-fb), w10 = fg*(1.f-fb), w01 = (1.f-fg)*fb, w11 = fg*fb;
    rp[j] = w00*cr00 + w10*cr10 + w01*cr01 + w11*cr11 + r;
    gp[j] = w00*cg00 + w10*cg10 + w01*cg01 + w11*cg11 + g;
    bp[j] = w00*cb00 + w10*cb10 + w01*cb01 + w11*cb11 + b;
  }
  float* ob = out + (size_t)bt*3*NPX;
  *((float4*)ob + v) = ro;
  *((float4*)(ob + NPX) + v) = go;
  *((float4*)(ob + 2*NPX) + v) = bo;
}

// ---------------- launcher ----------------
extern "C" void kernel_launch(void* const* d_in, const int* in_sizes, int n_in,
                              void* d_out, int out_size, void* d_ws, size_t ws_size,
                              hipStream_t stream) {
  const float* img     = (const float*)d_in[0];
  const float* img_org = (const float*)d_in[1];
  const float* c0w = (const float*)d_in[2];  const float* c0b = (const float*)d_in[3];
  const float* c1w = (const float*)d_in[4];  const float* c1b = (const float*)d_in[5];
  const float* c2w = (const float*)d_in[6];  const float* c2b = (const float*)d_in[7];
  const float* c3w = (const float*)d_in[8];  const float* c3b = (const float*)d_in[9];
  const float* c4w = (const float*)d_in[10]; const float* c4b = (const float*)d_in[11];
  const float* n0g = (const float*)d_in[12]; const float* n0b = (const float*)d_in[13];
  const float* n1g = (const float*)d_in[14]; const float* n1b = (const float*)d_in[15];
  const float* n2g = (const float*)d_in[16]; const float* n2b = (const float*)d_in[17];
  const float* n3g = (const float*)d_in[18]; const float* n3b = (const float*)d_in[19];
  const float* cls0_w = (const float*)d_in[20]; const float* cls0_b = (const float*)d_in[21];
  const float* cls1_w = (const float*)d_in[22]; const float* cls1_b = (const float*)d_in[23];
  const float* s_layers = (const float*)d_in[24];
  const float* w_layers = (const float*)d_in[25];
  const float* luts     = (const float*)d_in[26];
  float* ws = (float*)d_ws;
  float* out = (float*)d_out;

  // zero STAT0/1/2 (1792 floats at head of Y3; Y3 is written only by conv3, later)
  zero_k<<<7, 256, 0, stream>>>(ws + OFF_STAT0, 1792);

  // conv0: 3->16, 256->128, SPLIT=8
  conv_s2<3, 16, 256, 256, 512, 8, true><<<8*16*8, 512, 0, stream>>>(
      img, c0w, c0b, nullptr, ws + OFF_Y0, ws + OFF_STAT0);
  finalize_k<16, 128*128><<<1, 256, 0, stream>>>(
      ws + OFF_STAT0, n0g, n0b, ws + OFF_SS0, nullptr, 0);

  // conv1: 16->32, 128->64, SPLIT=4 ; finalize1 also zeroes STAT3 (in now-dead Y0)
  conv_s2<16, 32, 128, 128, 256, 4, false><<<8*32*4, 256, 0, stream>>>(
      ws + OFF_Y0, c1w, c1b, ws + OFF_SS0, ws + OFF_Y1, ws + OFF_STAT1);
  finalize_k<32, 64*64><<<8, 256, 0, stream>>>(
      ws + OFF_STAT1, n1g, n1b, ws + OFF_SS1, ws + OFF_STAT3, 2048);

  // conv2: 32->64, 64->32
  conv_s2<32, 64, 64, 64, 256, 1, false><<<8*64, 256, 0, stream>>>(
      ws + OFF_Y1, c2w, c2b, ws + OFF_SS1, ws + OFF_Y2, ws + OFF_STAT2);
  finalize_k<64, 32*32><<<2, 256, 0, stream>>>(
      ws + OFF_STAT2, n2g, n2b, ws + OFF_SS2, nullptr, 0);

  // conv3: 64->128, 32->16
  conv_s2<64, 128, 32, 32, 64, 1, false><<<8*128, 64, 0, stream>>>(
      ws + OFF_Y2, c3w, c3b, ws + OFF_SS2, ws + OFF_Y3, ws + OFF_STAT3);
  finalize_k<128, 16*16><<<4, 256, 0, stream>>>(
      ws + OFF_STAT3, n3g, n3b, ws + OFF_SS3, nullptr, 0);

  // conv4 + global mean -> feat
  conv_s2_last<<<8*128, 64, 0, stream>>>(
      ws + OFF_Y3, c4w, c4b, ws + OFF_SS3, ws + OFF_FEAT);

  head_kernel<<<1, 256, 0, stream>>>(
      ws + OFF_FEAT, cls0_w, cls0_b, cls1_w, cls1_b, ws + OFF_WGT);
  tmat_kernel<<<dim3(5, 300), 256, 0, stream>>>(luts, w_layers, ws + OFF_T);
  lut_kernel<<<141*8, 256, 0, stream>>>(
      ws + OFF_T, ws + OFF_WGT, s_layers, (float4*)(ws + OFF_LUT4));
  trilin_kernel<<<900*8, 256, 0, stream>>>(
      img_org, (const float4*)(ws + OFF_LUT4), out);
}

// Round 3
// 347.661 us; speedup vs baseline: 2.7269x; 2.7269x over previous
//
#include <hip/hip_runtime.h>
#include <hip/hip_fp16.h>

// ---------------- workspace layout (float offsets) ----------------
constexpr size_t OFF_Y0   = 0;         // 8*16*128*128 = 2097152
constexpr size_t OFF_Y1   = 2097152;   // 8*32*64*64   = 1048576
constexpr size_t OFF_Y2   = 3145728;   // 8*64*32*32   = 524288
constexpr size_t OFF_Y3   = 3670016;   // 8*128*16*16  = 262144
constexpr size_t OFF_FEAT = 3936000;   // (unused now)
constexpr size_t OFF_WGT  = 3937024;   // 8*20 (padded)
constexpr size_t OFF_T    = 3937280;   // 300*1089 = 326700
constexpr size_t OFF_LUT4 = 4264064;   // 8*35937 entries * 16B (fp16 r-pairs)
// STAT buffers live at the head of the T region: T is only written by
// tmat_kernel which launches AFTER head_kernel consumed featsum.
constexpr size_t OFF_STAT0 = OFF_T + 0;     // 8*16*2  = 256
constexpr size_t OFF_STAT1 = OFF_T + 256;   // 8*32*2  = 512
constexpr size_t OFF_STAT2 = OFF_T + 768;   // 8*64*2  = 1024
constexpr size_t OFF_STAT3 = OFF_T + 1792;  // 8*128*2 = 2048
constexpr size_t OFF_FEATS = OFF_T + 3840;  // 8*128   = 1024
// total stat block = 4864 floats

__global__ __launch_bounds__(256) void zero_k(float* __restrict__ p, int n) {
  int i = blockIdx.x*256 + threadIdx.x;
  if (i < n) p[i] = 0.f;
}

// ---------------- unified tiled conv: stride-2 3x3 + lrelu (+stats / +mean) ----------------
// Block = (b, tile of TH output rows, oc-block of OCG channels).
// LDS holds the normalized, zero-padded input tile, even/odd column split:
//   per (ic,row): E[j] = xn[col 2j] (j=0..WIN/2, col WIN pad=0), at rowbase+0
//                 O[j] = xn[col 2j-1] (j=0..WIN/2),              at rowbase+SEG
// Output px c taps: kx0 -> O[c], kx1 -> E[c], kx2 -> O[c+1].
// Weights stream from global (L2) with a register double-buffer.
// MODE: 0 = first (MEAN/STD norm), 1 = mid (inorm from raw stats), 2 = last (no y, mean->featsum)
template<int CIN, int COUT, int HIN, int WIN, int TH, int OCG, int PX, int OCT,
         int BLK, int MODE, int NPXPREV>
__global__ __launch_bounds__(BLK) void conv_tile(
    const float* __restrict__ xin, const float* __restrict__ wgt,
    const float* __restrict__ bias, const float* __restrict__ stat_in,
    const float* __restrict__ gam, const float* __restrict__ bet,
    float* __restrict__ yout, float* __restrict__ stat_out)
{
  constexpr int HOUT = HIN/2, WOUT = WIN/2;
  constexpr int SEG  = WOUT + 4;          // %4 == 0 for all layers
  constexpr int XROW = 2*SEG;
  constexpr int XPI  = (2*TH+1)*XROW;     // floats per ic
  constexpr int NT   = HOUT/TH;
  constexpr int NOCB = COUT/OCG;
  constexpr int NSTRIP_B = TH*WOUT/PX;
  constexpr int GPT  = OCG/OCT;
  static_assert(BLK == NSTRIP_B*GPT, "thread mapping mismatch");
  constexpr int R = NSTRIP_B < 64 ? NSTRIP_B : 64;

  __shared__ __align__(16) float xs[CIN*XPI];
  __shared__ float s_sc[CIN], s_sf[CIN];

  const int tid = threadIdx.x;
  const int lin = blockIdx.x;
  const int b = lin & 7;
  const int r2 = lin >> 3;
  const int tile = r2 % NT;
  const int ocb  = r2 / NT;

  // ---- per-input-channel normalization (prev inorm folded) ----
  if constexpr (MODE == 0) {
    if (tid == 0) { s_sc[0] = 1.f/0.229f; s_sf[0] = -0.485f/0.229f; }
    else if (tid == 1) { s_sc[1] = 1.f/0.224f; s_sf[1] = -0.456f/0.224f; }
    else if (tid == 2) { s_sc[2] = 1.f/0.225f; s_sf[2] = -0.406f/0.225f; }
  } else {
    if (tid < CIN) {
      float S = stat_in[(b*CIN+tid)*2+0], Q = stat_in[(b*CIN+tid)*2+1];
      float mean = S*(1.0f/NPXPREV);
      float var  = Q*(1.0f/NPXPREV) - mean*mean;
      float rstd = rsqrtf(var + 1e-5f);
      float gg = gam[tid], bb = bet[tid];
      s_sc[tid] = gg*rstd;
      s_sf[tid] = bb - mean*gg*rstd;
    }
  }
  __syncthreads();

  // ---- stage normalized, padded, even/odd-split input tile ----
  const int iy0 = tile*(2*TH) - 1;
  const float* xb_g = xin + (size_t)b*CIN*HIN*WIN;
  for (int e = tid; e < CIN*(2*TH+1)*(WIN+2); e += BLK) {
    int ic  = e / ((2*TH+1)*(WIN+2));
    int rem = e - ic*((2*TH+1)*(WIN+2));
    int rr  = rem / (WIN+2);
    int cc  = rem - rr*(WIN+2);
    int iy = iy0 + rr, ix = cc - 1;
    float v = 0.f;
    if (iy >= 0 && iy < HIN && ix >= 0 && ix < WIN)
      v = s_sc[ic]*xb_g[ic*HIN*WIN + iy*WIN + ix] + s_sf[ic];
    int off = (ix & 1) ? (SEG + ((ix+1) >> 1)) : (ix >> 1);
    xs[ic*XPI + rr*XROW + off] = v;
  }
  __syncthreads();

  // ---- per-thread assignment ----
  const int s  = tid % NSTRIP_B;
  const int g  = tid / NSTRIP_B;
  const int r  = s / (WOUT/PX);
  const int c0 = (s % (WOUT/PX)) * PX;
  const int oc0 = ocb*OCG + g*OCT;

  float acc[OCT][PX];
  #pragma unroll
  for (int k = 0; k < OCT; ++k) {
    float bb = bias[oc0+k];
    #pragma unroll
    for (int j = 0; j < PX; ++j) acc[k][j] = bb;
  }

  // weight double-buffer
  float wv[OCT][9];
  #pragma unroll
  for (int k = 0; k < OCT; ++k) {
    const float* wp = wgt + ((size_t)(oc0+k)*CIN)*9;
    #pragma unroll
    for (int t = 0; t < 9; ++t) wv[k][t] = wp[t];
  }

  for (int ic = 0; ic < CIN; ++ic) {
    float wn[OCT][9];
    if (ic + 1 < CIN) {
      #pragma unroll
      for (int k = 0; k < OCT; ++k) {
        const float* wp = wgt + ((size_t)(oc0+k)*CIN + ic + 1)*9;
        #pragma unroll
        for (int t = 0; t < 9; ++t) wn[k][t] = wp[t];
      }
    }
    const float* xb = xs + ic*XPI;
    #pragma unroll
    for (int ky = 0; ky < 3; ++ky) {
      const float* rowp = xb + (2*r+ky)*XROW;
      float eb[PX], ob[PX+1];
      if constexpr (PX == 8) {
        *(float4*)&eb[0] = *(const float4*)(rowp + c0);
        *(float4*)&eb[4] = *(const float4*)(rowp + c0 + 4);
        *(float4*)&ob[0] = *(const float4*)(rowp + SEG + c0);
        *(float4*)&ob[4] = *(const float4*)(rowp + SEG + c0 + 4);
        ob[8] = rowp[SEG + c0 + 8];
      } else if constexpr (PX == 4) {
        *(float4*)&eb[0] = *(const float4*)(rowp + c0);
        *(float4*)&ob[0] = *(const float4*)(rowp + SEG + c0);
        ob[4] = rowp[SEG + c0 + 4];
      } else if constexpr (PX == 2) {
        *(float2*)&eb[0] = *(const float2*)(rowp + c0);
        *(float2*)&ob[0] = *(const float2*)(rowp + SEG + c0);
        ob[2] = rowp[SEG + c0 + 2];
      } else {
        eb[0] = rowp[c0];
        ob[0] = rowp[SEG + c0];
        ob[1] = rowp[SEG + c0 + 1];
      }
      #pragma unroll
      for (int k = 0; k < OCT; ++k) {
        float w0 = wv[k][ky*3], w1 = wv[k][ky*3+1], w2 = wv[k][ky*3+2];
        #pragma unroll
        for (int j = 0; j < PX; ++j)
          acc[k][j] += w0*ob[j] + w1*eb[j] + w2*ob[j+1];
      }
    }
    if (ic + 1 < CIN) {
      #pragma unroll
      for (int k = 0; k < OCT; ++k)
        #pragma unroll
        for (int t = 0; t < 9; ++t) wv[k][t] = wn[k][t];
    }
  }

  // ---- lrelu + output + stats ----
  const int oy = tile*TH + r;
  if constexpr (MODE != 2) {
    float lsum[OCT], lsq[OCT];
    #pragma unroll
    for (int k = 0; k < OCT; ++k) {
      float ov[PX];
      float ls = 0.f, lq = 0.f;
      #pragma unroll
      for (int j = 0; j < PX; ++j) {
        float a = acc[k][j];
        a = a >= 0.f ? a : 0.2f*a;
        ov[j] = a; ls += a; lq += a*a;
      }
      lsum[k] = ls; lsq[k] = lq;
      float* yp = yout + (((size_t)b*COUT + oc0 + k)*HOUT + oy)*WOUT + c0;
      if constexpr (PX == 8) {
        *(float4*)yp = *(float4*)&ov[0];
        *(float4*)(yp+4) = *(float4*)&ov[4];
      } else if constexpr (PX == 4) {
        *(float4*)yp = *(float4*)&ov[0];
      } else if constexpr (PX == 2) {
        *(float2*)yp = *(float2*)&ov[0];
      } else {
        *yp = ov[0];
      }
    }
    #pragma unroll
    for (int k = 0; k < OCT; ++k) {
      #pragma unroll
      for (int off = R/2; off > 0; off >>= 1) {
        lsum[k] += __shfl_down(lsum[k], off);
        lsq[k]  += __shfl_down(lsq[k],  off);
      }
    }
    if ((tid & (R-1)) == 0) {
      #pragma unroll
      for (int k = 0; k < OCT; ++k) {
        atomicAdd(&stat_out[(b*COUT + oc0 + k)*2 + 0], lsum[k]);
        atomicAdd(&stat_out[(b*COUT + oc0 + k)*2 + 1], lsq[k]);
      }
    }
  } else {
    // last conv: lrelu then sum over the 8x8 plane -> featsum atomics
    float a = acc[0][0];
    a = a >= 0.f ? a : 0.2f*a;
    #pragma unroll
    for (int off = R/2; off > 0; off >>= 1) a += __shfl_down(a, off);
    if ((tid & (R-1)) == 0) atomicAdd(&stat_out[b*COUT + oc0], a);
  }
}

// ---------------- classifier head (featsum -> weights) ----------------
__global__ __launch_bounds__(256) void head_kernel(
    const float* __restrict__ featsum, const float* __restrict__ w0, const float* __restrict__ b0,
    const float* __restrict__ w1, const float* __restrict__ b1, float* __restrict__ wout)
{
  __shared__ float sh_h[8*128];
  const int tid = threadIdx.x;
  for (int i = tid; i < 8*128; i += 256) {
    int b = i >> 7, t = i & 127;
    const float* f = featsum + b*128;
    const float* w = w0 + t*128;
    float a = 0.f;
    for (int k = 0; k < 128; ++k) a += f[k]*w[k];
    a = b0[t] + a*(1.0f/64.0f);          // fold the mean's 1/64
    float c = fminf(fmaxf(a + 3.f, 0.f), 6.f);
    sh_h[i] = a * c * (1.f/6.f);         // hardswish
  }
  __syncthreads();
  for (int i = tid; i < 8*20; i += 256) {
    int b = i/20, n = i - b*20;
    const float* h = sh_h + b*128;
    const float* w = w1 + n*128;
    float a = b1[n];
    for (int k = 0; k < 128; ++k) a += h[k]*w[k];
    wout[b*20 + n] = a;
  }
}

// ---------------- T = luts(300x20) @ w_layers(20x1089) ----------------
__global__ __launch_bounds__(256) void tmat_kernel(
    const float* __restrict__ luts, const float* __restrict__ wl, float* __restrict__ T)
{
  int q = blockIdx.x*256 + threadIdx.x;
  int row = blockIdx.y;
  if (q >= 1089) return;
  float a = 0.f;
  #pragma unroll
  for (int w = 0; w < 20; ++w) a += luts[row*20 + w] * wl[w*1089 + q];
  T[row*1089 + q] = a;
}

// ---------------- per-batch 3D LUT, fp16 r-corner pairs, 16B per (b,g,r) entry -------------
__global__ __launch_bounds__(256) void lut_kernel(
    const float* __restrict__ T, const float* __restrict__ wgt,
    const float* __restrict__ slay, float4* __restrict__ lut)
{
  const int lin = blockIdx.x;
  const int bt = lin & 7;
  const int i = (lin >> 3)*256 + threadIdx.x;
  if (i >= 35937) return;
  int bi = i / 1089, rem = i - bi*1089, gi = rem / 33, ri = rem - gi*33;
  int r1 = ri < 32 ? ri + 1 : 32;
  float w[20];
  #pragma unroll
  for (int n = 0; n < 20; ++n) w[n] = wgt[bt*20 + n];

  float ch0_a = 0.f, ch0_b = 0.f;
  {
    int q = bi*33 + gi;
    #pragma unroll
    for (int s = 0; s < 5; ++s) {
      float t = 0.f;
      #pragma unroll
      for (int n = 0; n < 20; ++n) t += w[n] * T[(s*60 + n*3 + 0)*1089 + q];
      ch0_a += slay[ri*5 + s]*t;
      ch0_b += slay[r1*5 + s]*t;
    }
  }
  float ch1_v[2], ch2_v[2];
  #pragma unroll
  for (int k = 0; k < 2; ++k) {
    int rr = k ? r1 : ri;
    float v1 = 0.f, v2 = 0.f;
    #pragma unroll
    for (int s = 0; s < 5; ++s) {
      float t1 = 0.f, t2 = 0.f;
      #pragma unroll
      for (int n = 0; n < 20; ++n) {
        t1 += w[n] * T[(s*60 + n*3 + 1)*1089 + bi*33 + rr];
        t2 += w[n] * T[(s*60 + n*3 + 2)*1089 + gi*33 + rr];
      }
      v1 += slay[gi*5 + s]*t1;
      v2 += slay[bi*5 + s]*t2;
    }
    ch1_v[k] = v1; ch2_v[k] = v2;
  }
  union { float4 f4; __half h[8]; } u;
  u.h[0] = __float2half(ch0_a); u.h[1] = __float2half(ch1_v[0]);
  u.h[2] = __float2half(ch2_v[0]); u.h[3] = __half(0.f);
  u.h[4] = __float2half(ch0_b); u.h[5] = __float2half(ch1_v[1]);
  u.h[6] = __float2half(ch2_v[1]); u.h[7] = __half(0.f);
  lut[(size_t)bt*35937 + i] = u.f4;
}

// ---------------- trilinear apply + residual (4 gathers/px) ----------------
__global__ __launch_bounds__(256) void trilin_kernel(
    const float* __restrict__ img, const float4* __restrict__ lut, float* __restrict__ out)
{
  constexpr int NPX = 720*1280;
  const int lin = blockIdx.x;
  const int bt = lin & 7;
  const int v = (lin >> 3)*256 + threadIdx.x;   // < NPX/4 exactly (900*256)
  const float* ib = img + (size_t)bt*3*NPX;
  float4 r4 = *((const float4*)ib + v);
  float4 g4 = *((const float4*)(ib + NPX) + v);
  float4 b4 = *((const float4*)(ib + 2*NPX) + v);
  const float4* L = lut + (size_t)bt*35937;
  const float invbin = 32.0f/1.000001f;
  float4 ro, go, bo;
  float* rp = (float*)&ro; float* gp = (float*)&go; float* bp = (float*)&bo;
  #pragma unroll
  for (int j = 0; j < 4; ++j) {
    float r = ((float*)&r4)[j], g = ((float*)&g4)[j], b = ((float*)&b4)[j];
    float pr = r*invbin, pg = g*invbin, pb = b*invbin;
    int ri = (int)pr; ri = ri > 31 ? 31 : ri; ri = ri < 0 ? 0 : ri;
    int gi = (int)pg; gi = gi > 31 ? 31 : gi; gi = gi < 0 ? 0 : gi;
    int bi = (int)pb; bi = bi > 31 ? 31 : bi; bi = bi < 0 ? 0 : bi;
    float fr = pr - ri, fg = pg - gi, fb = pb - bi;
    int base = (bi*33 + gi)*33 + ri;
    float4 q00 = L[base];        // (g0,b0)
    float4 q10 = L[base+33];     // (g1,b0)
    float4 q01 = L[base+1089];   // (g0,b1)
    float4 q11 = L[base+1122];   // (g1,b1)
    const __half2* h00 = (const __half2*)&q00;
    const __half2* h10 = (const __half2*)&q10;
    const __half2* h01 = (const __half2*)&q01;
    const __half2* h11 = (const __half2*)&q11;
    float2 a00 = __half22float2(h00[0]), e00 = __half22float2(h00[1]);
    float2 c00 = __half22float2(h00[2]), d00 = __half22float2(h00[3]);
    float2 a10 = __half22float2(h10[0]), e10 = __half22float2(h10[1]);
    float2 c10 = __half22float2(h10[2]), d10 = __half22float2(h10[3]);
    float2 a01 = __half22float2(h01[0]), e01 = __half22float2(h01[1]);
    float2 c01 = __half22float2(h01[2]), d01 = __half22float2(h01[3]);
    float2 a11 = __half22float2(h11[0]), e11 = __half22float2(h11[1]);
    float2 c11 = __half22float2(h11[2]), d11 = __half22float2(h11[3]);
    float cr00 = a00.x + fr*(c00.x - a00.x), cg00 = a00.y + fr*(c00.y - a00.y), cb00 = e00.x + fr*(d00.x - e00.x);
    float cr10 = a10.x + fr*(c10.x - a10.x), cg10 = a10.y + fr*(c10.y - a10.y), cb10 = e10.x + fr*(d10.x - e10.x);
    float cr01 = a01.x + fr*(c01.x - a01.x), cg01 = a01.y + fr*(c01.y - a01.y), cb01 = e01.x + fr*(d01.x - e01.x);
    float cr11 = a11.x + fr*(c11.x - a11.x), cg11 = a11.y + fr*(c11.y - a11.y), cb11 = e11.x + fr*(d11.x - e11.x);
    float w00 = (1.f-fg)*(1.f-fb), w10 = fg*(1.f-fb), w01 = (1.f-fg)*fb, w11 = fg*fb;
    rp[j] = w00*cr00 + w10*cr10 + w01*cr01 + w11*cr11 + r;
    gp[j] = w00*cg00 + w10*cg10 + w01*cg01 + w11*cg11 + g;
    bp[j] = w00*cb00 + w10*cb10 + w01*cb01 + w11*cb11 + b;
  }
  float* ob = out + (size_t)bt*3*NPX;
  *((float4*)ob + v) = ro;
  *((float4*)(ob + NPX) + v) = go;
  *((float4*)(ob + 2*NPX) + v) = bo;
}

// ---------------- launcher ----------------
extern "C" void kernel_launch(void* const* d_in, const int* in_sizes, int n_in,
                              void* d_out, int out_size, void* d_ws, size_t ws_size,
                              hipStream_t stream) {
  const float* img     = (const float*)d_in[0];
  const float* img_org = (const float*)d_in[1];
  const float* c0w = (const float*)d_in[2];  const float* c0b = (const float*)d_in[3];
  const float* c1w = (const float*)d_in[4];  const float* c1b = (const float*)d_in[5];
  const float* c2w = (const float*)d_in[6];  const float* c2b = (const float*)d_in[7];
  const float* c3w = (const float*)d_in[8];  const float* c3b = (const float*)d_in[9];
  const float* c4w = (const float*)d_in[10]; const float* c4b = (const float*)d_in[11];
  const float* n0g = (const float*)d_in[12]; const float* n0b = (const float*)d_in[13];
  const float* n1g = (const float*)d_in[14]; const float* n1b = (const float*)d_in[15];
  const float* n2g = (const float*)d_in[16]; const float* n2b = (const float*)d_in[17];
  const float* n3g = (const float*)d_in[18]; const float* n3b = (const float*)d_in[19];
  const float* cls0_w = (const float*)d_in[20]; const float* cls0_b = (const float*)d_in[21];
  const float* cls1_w = (const float*)d_in[22]; const float* cls1_b = (const float*)d_in[23];
  const float* s_layers = (const float*)d_in[24];
  const float* w_layers = (const float*)d_in[25];
  const float* luts     = (const float*)d_in[26];
  float* ws = (float*)d_ws;
  float* out = (float*)d_out;

  // zero all stat buffers + featsum (head of T region, dead until tmat)
  zero_k<<<19, 256, 0, stream>>>(ws + OFF_T, 4864);

  // conv0: 3->16, 256->128. TH=8, OCG=16(all), PX=8, OCT=4, 512 thr, 128 blocks
  conv_tile<3,16,256,256, 8,16, 8,4, 512, 0, 1><<<128, 512, 0, stream>>>(
      img, c0w, c0b, nullptr, nullptr, nullptr, ws + OFF_Y0, ws + OFF_STAT0);

  // conv1: 16->32, 128->64. TH=2, OCG=32(all), PX=4, OCT=4, 256 thr, 256 blocks
  conv_tile<16,32,128,128, 2,32, 4,4, 256, 1, 16384><<<256, 256, 0, stream>>>(
      ws + OFF_Y0, c1w, c1b, ws + OFF_STAT0, n0g, n0b, ws + OFF_Y1, ws + OFF_STAT1);

  // conv2: 32->64, 64->32. TH=2, OCG=32, nocb=2, PX=4, OCT=2, 256 thr, 256 blocks
  conv_tile<32,64,64,64, 2,32, 4,2, 256, 1, 4096><<<256, 256, 0, stream>>>(
      ws + OFF_Y1, c2w, c2b, ws + OFF_STAT1, n1g, n1b, ws + OFF_Y2, ws + OFF_STAT2);

  // conv3: 64->128, 32->16. TH=2, OCG=32, nocb=4, PX=2, OCT=2, 256 thr, 256 blocks
  conv_tile<64,128,32,32, 2,32, 2,2, 256, 1, 1024><<<256, 256, 0, stream>>>(
      ws + OFF_Y2, c3w, c3b, ws + OFF_STAT2, n2g, n2b, ws + OFF_Y3, ws + OFF_STAT3);

  // conv4: 128->128, 16->8, mean -> featsum. TH=2, OCG=16, nocb=8, PX=1, OCT=1
  conv_tile<128,128,16,16, 2,16, 1,1, 256, 2, 256><<<256, 256, 0, stream>>>(
      ws + OFF_Y3, c4w, c4b, ws + OFF_STAT3, n3g, n3b, nullptr, ws + OFF_FEATS);

  head_kernel<<<1, 256, 0, stream>>>(
      ws + OFF_FEATS, cls0_w, cls0_b, cls1_w, cls1_b, ws + OFF_WGT);
  tmat_kernel<<<dim3(5, 300), 256, 0, stream>>>(luts, w_layers, ws + OFF_T);
  lut_kernel<<<141*8, 256, 0, stream>>>(
      ws + OFF_T, ws + OFF_WGT, s_layers, (float4*)(ws + OFF_LUT4));
  trilin_kernel<<<900*8, 256, 0, stream>>>(
      img_org, (const float4*)(ws + OFF_LUT4), out);
}

// Round 4
// 298.449 us; speedup vs baseline: 3.1765x; 1.1649x over previous
//
#include <hip/hip_runtime.h>
#include <hip/hip_fp16.h>

// ---------------- workspace layout (float offsets) ----------------
// Expanded LUT (written late, by lut_expand) overlaps Y0..Y3 (dead by then).
constexpr size_t OFF_Y0    = 0;         // 8*16*128*128 = 2097152
constexpr size_t OFF_Y1    = 2097152;   // 8*32*64*64   = 1048576
constexpr size_t OFF_Y2    = 3145728;   // 8*64*32*32   = 524288
constexpr size_t OFF_Y3    = 3670016;   // 8*128*16*16  = 262144 (ends 3932160)
constexpr size_t OFF_LUT64 = 0;         // 8*35937*16 floats = 4599936 (64B entries)
constexpr size_t OFF_T     = 4599936;   // 300*1089 = 326700 (ends 4926636)
constexpr size_t OFF_STATB = 4926640;
constexpr size_t OFF_STAT0 = OFF_STATB + 0;     // 8*16*2  = 256
constexpr size_t OFF_STAT1 = OFF_STATB + 256;   // 8*32*2  = 512
constexpr size_t OFF_STAT2 = OFF_STATB + 768;   // 8*64*2  = 1024
constexpr size_t OFF_STAT3 = OFF_STATB + 1792;  // 8*128*2 = 2048
constexpr size_t OFF_FEATS = OFF_STATB + 3840;  // 8*128   = 1024
constexpr size_t OFF_WGT   = OFF_STATB + 4864;  // 8*20 -> 256
constexpr size_t OFF_LUTC  = 4931760;   // compact fp16 LUT: 8*35937*2 = 574992
// total = 5506752 floats ~= 22.0 MB

__global__ __launch_bounds__(256) void zero_k(float* __restrict__ p, int n) {
  int i = blockIdx.x*256 + threadIdx.x;
  if (i < n) p[i] = 0.f;
}

// ---------------- unified tiled conv: stride-2 3x3 + lrelu (+stats / +mean) ----------------
template<int CIN, int COUT, int HIN, int WIN, int TH, int OCG, int PX, int OCT,
         int BLK, int MODE, int NPXPREV>
__global__ __launch_bounds__(BLK) void conv_tile(
    const float* __restrict__ xin, const float* __restrict__ wgt,
    const float* __restrict__ bias, const float* __restrict__ stat_in,
    const float* __restrict__ gam, const float* __restrict__ bet,
    float* __restrict__ yout, float* __restrict__ stat_out)
{
  constexpr int HOUT = HIN/2, WOUT = WIN/2;
  constexpr int SEG  = WOUT + 4;
  constexpr int XROW = 2*SEG;
  constexpr int XPI  = (2*TH+1)*XROW;
  constexpr int NT   = HOUT/TH;
  constexpr int NSTRIP_B = TH*WOUT/PX;
  constexpr int GPT  = OCG/OCT;
  static_assert(BLK == NSTRIP_B*GPT, "thread mapping mismatch");
  constexpr int R = NSTRIP_B < 64 ? NSTRIP_B : 64;

  __shared__ __align__(16) float xs[CIN*XPI];
  __shared__ float s_sc[CIN], s_sf[CIN];

  const int tid = threadIdx.x;
  const int lin = blockIdx.x;
  const int b = lin & 7;
  const int r2 = lin >> 3;
  const int tile = r2 % NT;
  const int ocb  = r2 / NT;

  if constexpr (MODE == 0) {
    if (tid == 0) { s_sc[0] = 1.f/0.229f; s_sf[0] = -0.485f/0.229f; }
    else if (tid == 1) { s_sc[1] = 1.f/0.224f; s_sf[1] = -0.456f/0.224f; }
    else if (tid == 2) { s_sc[2] = 1.f/0.225f; s_sf[2] = -0.406f/0.225f; }
  } else {
    if (tid < CIN) {
      float S = stat_in[(b*CIN+tid)*2+0], Q = stat_in[(b*CIN+tid)*2+1];
      float mean = S*(1.0f/NPXPREV);
      float var  = Q*(1.0f/NPXPREV) - mean*mean;
      float rstd = rsqrtf(var + 1e-5f);
      float gg = gam[tid], bb = bet[tid];
      s_sc[tid] = gg*rstd;
      s_sf[tid] = bb - mean*gg*rstd;
    }
  }
  __syncthreads();

  const int iy0 = tile*(2*TH) - 1;
  const float* xb_g = xin + (size_t)b*CIN*HIN*WIN;
  for (int e = tid; e < CIN*(2*TH+1)*(WIN+2); e += BLK) {
    int ic  = e / ((2*TH+1)*(WIN+2));
    int rem = e - ic*((2*TH+1)*(WIN+2));
    int rr  = rem / (WIN+2);
    int cc  = rem - rr*(WIN+2);
    int iy = iy0 + rr, ix = cc - 1;
    float v = 0.f;
    if (iy >= 0 && iy < HIN && ix >= 0 && ix < WIN)
      v = s_sc[ic]*xb_g[ic*HIN*WIN + iy*WIN + ix] + s_sf[ic];
    int off = (ix & 1) ? (SEG + ((ix+1) >> 1)) : (ix >> 1);
    xs[ic*XPI + rr*XROW + off] = v;
  }
  __syncthreads();

  const int s  = tid % NSTRIP_B;
  const int g  = tid / NSTRIP_B;
  const int r  = s / (WOUT/PX);
  const int c0 = (s % (WOUT/PX)) * PX;
  const int oc0 = ocb*OCG + g*OCT;

  float acc[OCT][PX];
  #pragma unroll
  for (int k = 0; k < OCT; ++k) {
    float bb = bias[oc0+k];
    #pragma unroll
    for (int j = 0; j < PX; ++j) acc[k][j] = bb;
  }

  float wv[OCT][9];
  #pragma unroll
  for (int k = 0; k < OCT; ++k) {
    const float* wp = wgt + ((size_t)(oc0+k)*CIN)*9;
    #pragma unroll
    for (int t = 0; t < 9; ++t) wv[k][t] = wp[t];
  }

  for (int ic = 0; ic < CIN; ++ic) {
    float wn[OCT][9];
    if (ic + 1 < CIN) {
      #pragma unroll
      for (int k = 0; k < OCT; ++k) {
        const float* wp = wgt + ((size_t)(oc0+k)*CIN + ic + 1)*9;
        #pragma unroll
        for (int t = 0; t < 9; ++t) wn[k][t] = wp[t];
      }
    }
    const float* xb = xs + ic*XPI;
    #pragma unroll
    for (int ky = 0; ky < 3; ++ky) {
      const float* rowp = xb + (2*r+ky)*XROW;
      float eb[PX], ob[PX+1];
      if constexpr (PX == 8) {
        *(float4*)&eb[0] = *(const float4*)(rowp + c0);
        *(float4*)&eb[4] = *(const float4*)(rowp + c0 + 4);
        *(float4*)&ob[0] = *(const float4*)(rowp + SEG + c0);
        *(float4*)&ob[4] = *(const float4*)(rowp + SEG + c0 + 4);
        ob[8] = rowp[SEG + c0 + 8];
      } else if constexpr (PX == 4) {
        *(float4*)&eb[0] = *(const float4*)(rowp + c0);
        *(float4*)&ob[0] = *(const float4*)(rowp + SEG + c0);
        ob[4] = rowp[SEG + c0 + 4];
      } else if constexpr (PX == 2) {
        *(float2*)&eb[0] = *(const float2*)(rowp + c0);
        *(float2*)&ob[0] = *(const float2*)(rowp + SEG + c0);
        ob[2] = rowp[SEG + c0 + 2];
      } else {
        eb[0] = rowp[c0];
        ob[0] = rowp[SEG + c0];
        ob[1] = rowp[SEG + c0 + 1];
      }
      #pragma unroll
      for (int k = 0; k < OCT; ++k) {
        float w0 = wv[k][ky*3], w1 = wv[k][ky*3+1], w2 = wv[k][ky*3+2];
        #pragma unroll
        for (int j = 0; j < PX; ++j)
          acc[k][j] += w0*ob[j] + w1*eb[j] + w2*ob[j+1];
      }
    }
    if (ic + 1 < CIN) {
      #pragma unroll
      for (int k = 0; k < OCT; ++k)
        #pragma unroll
        for (int t = 0; t < 9; ++t) wv[k][t] = wn[k][t];
    }
  }

  const int oy = tile*TH + r;
  if constexpr (MODE != 2) {
    float lsum[OCT], lsq[OCT];
    #pragma unroll
    for (int k = 0; k < OCT; ++k) {
      float ov[PX];
      float ls = 0.f, lq = 0.f;
      #pragma unroll
      for (int j = 0; j < PX; ++j) {
        float a = acc[k][j];
        a = a >= 0.f ? a : 0.2f*a;
        ov[j] = a; ls += a; lq += a*a;
      }
      lsum[k] = ls; lsq[k] = lq;
      float* yp = yout + (((size_t)b*COUT + oc0 + k)*HOUT + oy)*WOUT + c0;
      if constexpr (PX == 8) {
        *(float4*)yp = *(float4*)&ov[0];
        *(float4*)(yp+4) = *(float4*)&ov[4];
      } else if constexpr (PX == 4) {
        *(float4*)yp = *(float4*)&ov[0];
      } else if constexpr (PX == 2) {
        *(float2*)yp = *(float2*)&ov[0];
      } else {
        *yp = ov[0];
      }
    }
    #pragma unroll
    for (int k = 0; k < OCT; ++k) {
      #pragma unroll
      for (int off = R/2; off > 0; off >>= 1) {
        lsum[k] += __shfl_down(lsum[k], off);
        lsq[k]  += __shfl_down(lsq[k],  off);
      }
    }
    if ((tid & (R-1)) == 0) {
      #pragma unroll
      for (int k = 0; k < OCT; ++k) {
        atomicAdd(&stat_out[(b*COUT + oc0 + k)*2 + 0], lsum[k]);
        atomicAdd(&stat_out[(b*COUT + oc0 + k)*2 + 1], lsq[k]);
      }
    }
  } else {
    float a = acc[0][0];
    a = a >= 0.f ? a : 0.2f*a;
    #pragma unroll
    for (int off = R/2; off > 0; off >>= 1) a += __shfl_down(a, off);
    if ((tid & (R-1)) == 0) atomicAdd(&stat_out[b*COUT + oc0], a);
  }
}

// ---------------- classifier head (featsum -> weights) ----------------
__global__ __launch_bounds__(256) void head_kernel(
    const float* __restrict__ featsum, const float* __restrict__ w0, const float* __restrict__ b0,
    const float* __restrict__ w1, const float* __restrict__ b1, float* __restrict__ wout)
{
  __shared__ float sh_h[8*128];
  const int tid = threadIdx.x;
  for (int i = tid; i < 8*128; i += 256) {
    int b = i >> 7, t = i & 127;
    const float* f = featsum + b*128;
    const float* w = w0 + t*128;
    float a = 0.f;
    for (int k = 0; k < 128; ++k) a += f[k]*w[k];
    a = b0[t] + a*(1.0f/64.0f);
    float c = fminf(fmaxf(a + 3.f, 0.f), 6.f);
    sh_h[i] = a * c * (1.f/6.f);
  }
  __syncthreads();
  for (int i = tid; i < 8*20; i += 256) {
    int b = i/20, n = i - b*20;
    const float* h = sh_h + b*128;
    const float* w = w1 + n*128;
    float a = b1[n];
    for (int k = 0; k < 128; ++k) a += h[k]*w[k];
    wout[b*20 + n] = a;
  }
}

// ---------------- T = luts(300x20) @ w_layers(20x1089) ----------------
__global__ __launch_bounds__(256) void tmat_kernel(
    const float* __restrict__ luts, const float* __restrict__ wl, float* __restrict__ T)
{
  int q = blockIdx.x*256 + threadIdx.x;
  int row = blockIdx.y;
  if (q >= 1089) return;
  float a = 0.f;
  #pragma unroll
  for (int w = 0; w < 20; ++w) a += luts[row*20 + w] * wl[w*1089 + q];
  T[row*1089 + q] = a;
}

// ---------------- pass1: compact fp16 LUT, one corner per entry (8B) ----------------
// lutc[bt][i] = {r,g,b,0} halfs at grid point i=(bi,gi,ri)
// ch0: d0=ri, q=bi*33+gi | ch1: d0=gi, q=bi*33+ri | ch2: d0=bi, q=gi*33+ri
__global__ __launch_bounds__(256) void lutc_kernel(
    const float* __restrict__ T, const float* __restrict__ wgt,
    const float* __restrict__ slay, uint2* __restrict__ lutc)
{
  const int lin = blockIdx.x;
  const int bt = lin & 7;
  const int i = (lin >> 3)*256 + threadIdx.x;
  if (i >= 35937) return;
  int bi = i / 1089, rem = i - bi*1089, gi = rem / 33, ri = rem - gi*33;
  float w[20];
  #pragma unroll
  for (int n = 0; n < 20; ++n) w[n] = wgt[bt*20 + n];

  const int qv[3]  = { bi*33 + gi, bi*33 + ri, gi*33 + ri };
  const int d0v[3] = { ri, gi, bi };
  float outv[3];
  #pragma unroll
  for (int ch = 0; ch < 3; ++ch) {
    float val = 0.f;
    #pragma unroll
    for (int s = 0; s < 5; ++s) {
      float t = 0.f;
      #pragma unroll
      for (int n = 0; n < 20; ++n)
        t += w[n] * T[(s*60 + n*3 + ch)*1089 + qv[ch]];
      val += slay[d0v[ch]*5 + s] * t;
    }
    outv[ch] = val;
  }
  union { __half2 h2; unsigned u; } p0, p1;
  p0.h2 = __floats2half2_rn(outv[0], outv[1]);
  p1.h2 = __floats2half2_rn(outv[2], 0.f);
  lutc[(size_t)bt*35937 + i] = make_uint2(p0.u, p1.u);
}

// ---------------- pass2: expand to 64B entries holding all 8 corners ----------------
// entry(bt,i): halfs h[idx*3+ch], idx = db*4+dg*2+dr, pad to 32 halfs
__global__ __launch_bounds__(256) void lut_expand_kernel(
    const uint2* __restrict__ lutc, uint4* __restrict__ lut64)
{
  const int lin = blockIdx.x;
  const int bt = lin & 7;
  const int i = (lin >> 3)*256 + threadIdx.x;
  if (i >= 35937) return;
  int bi = i / 1089, rem = i - bi*1089, gi = rem / 33, ri = rem - gi*33;
  const int b1 = bi < 32 ? bi+1 : 32, g1 = gi < 32 ? gi+1 : 32, r1 = ri < 32 ? ri+1 : 32;
  const uint2* base = lutc + (size_t)bt*35937;
  union { unsigned short h[32]; uint4 q[4]; } u;
  #pragma unroll
  for (int t = 24; t < 32; ++t) u.h[t] = 0;
  const int bsel[2] = { bi, b1 }, gsel[2] = { gi, g1 }, rsel[2] = { ri, r1 };
  #pragma unroll
  for (int db = 0; db < 2; ++db)
    #pragma unroll
    for (int dg = 0; dg < 2; ++dg)
      #pragma unroll
      for (int dr = 0; dr < 2; ++dr) {
        const int idx = db*4 + dg*2 + dr;
        uint2 s = base[(bsel[db]*33 + gsel[dg])*33 + rsel[dr]];
        u.h[idx*3+0] = (unsigned short)(s.x & 0xffff);
        u.h[idx*3+1] = (unsigned short)(s.x >> 16);
        u.h[idx*3+2] = (unsigned short)(s.y & 0xffff);
      }
  uint4* dst = lut64 + ((size_t)bt*35937 + i)*4;
  dst[0] = u.q[0]; dst[1] = u.q[1]; dst[2] = u.q[2]; dst[3] = u.q[3];
}

// ---------------- trilinear apply + residual: 1 cache line per pixel ----------------
__global__ __launch_bounds__(256) void trilin_kernel(
    const float* __restrict__ img, const uint4* __restrict__ lut, float* __restrict__ out)
{
  constexpr int NPX = 720*1280;
  const int lin = blockIdx.x;
  const int bt = lin & 7;
  const int v = (lin >> 3)*256 + threadIdx.x;   // < NPX/4 exactly (900*256)
  const float* ib = img + (size_t)bt*3*NPX;
  float4 r4 = *((const float4*)ib + v);
  float4 g4 = *((const float4*)(ib + NPX) + v);
  float4 b4 = *((const float4*)(ib + 2*NPX) + v);
  const uint4* L = lut + (size_t)bt*35937*4;
  const float invbin = 32.0f/1.000001f;
  float4 ro, go, bo;
  float* rp = (float*)&ro; float* gp = (float*)&go; float* bp = (float*)&bo;
  #pragma unroll
  for (int j = 0; j < 4; ++j) {
    float r = ((float*)&r4)[j], g = ((float*)&g4)[j], b = ((float*)&b4)[j];
    float pr = r*invbin, pg = g*invbin, pb = b*invbin;
    int ri = (int)pr; ri = ri > 31 ? 31 : ri; ri = ri < 0 ? 0 : ri;
    int gi = (int)pg; gi = gi > 31 ? 31 : gi; gi = gi < 0 ? 0 : gi;
    int bi = (int)pb; bi = bi > 31 ? 31 : bi; bi = bi < 0 ? 0 : bi;
    float fr = pr - ri, fg = pg - gi, fb = pb - bi;
    const uint4* e = L + (size_t)((bi*33 + gi)*33 + ri)*4;
    union { uint4 q[3]; __half h[24]; } u;
    u.q[0] = e[0]; u.q[1] = e[1]; u.q[2] = e[2];
    float wr1 = fr, wr0 = 1.f-fr;
    float wg1 = fg, wg0 = 1.f-fg;
    float wb1 = fb, wb0 = 1.f-fb;
    float w00 = wb0*wg0, w01 = wb0*wg1, w10 = wb1*wg0, w11 = wb1*wg1;
    float wt[8] = { w00*wr0, w00*wr1, w01*wr0, w01*wr1,
                    w10*wr0, w10*wr1, w11*wr0, w11*wr1 };
    float rr = 0.f, gg = 0.f, bb2 = 0.f;
    #pragma unroll
    for (int idx = 0; idx < 8; ++idx) {
      float wv = wt[idx];
      rr  += wv * __half2float(u.h[idx*3+0]);
      gg  += wv * __half2float(u.h[idx*3+1]);
      bb2 += wv * __half2float(u.h[idx*3+2]);
    }
    rp[j] = rr + r; gp[j] = gg + g; bp[j] = bb2 + b;
  }
  float* ob = out + (size_t)bt*3*NPX;
  *((float4*)ob + v) = ro;
  *((float4*)(ob + NPX) + v) = go;
  *((float4*)(ob + 2*NPX) + v) = bo;
}

// ---------------- launcher ----------------
extern "C" void kernel_launch(void* const* d_in, const int* in_sizes, int n_in,
                              void* d_out, int out_size, void* d_ws, size_t ws_size,
                              hipStream_t stream) {
  const float* img     = (const float*)d_in[0];
  const float* img_org = (const float*)d_in[1];
  const float* c0w = (const float*)d_in[2];  const float* c0b = (const float*)d_in[3];
  const float* c1w = (const float*)d_in[4];  const float* c1b = (const float*)d_in[5];
  const float* c2w = (const float*)d_in[6];  const float* c2b = (const float*)d_in[7];
  const float* c3w = (const float*)d_in[8];  const float* c3b = (const float*)d_in[9];
  const float* c4w = (const float*)d_in[10]; const float* c4b = (const float*)d_in[11];
  const float* n0g = (const float*)d_in[12]; const float* n0b = (const float*)d_in[13];
  const float* n1g = (const float*)d_in[14]; const float* n1b = (const float*)d_in[15];
  const float* n2g = (const float*)d_in[16]; const float* n2b = (const float*)d_in[17];
  const float* n3g = (const float*)d_in[18]; const float* n3b = (const float*)d_in[19];
  const float* cls0_w = (const float*)d_in[20]; const float* cls0_b = (const float*)d_in[21];
  const float* cls1_w = (const float*)d_in[22]; const float* cls1_b = (const float*)d_in[23];
  const float* s_layers = (const float*)d_in[24];
  const float* w_layers = (const float*)d_in[25];
  const float* luts     = (const float*)d_in[26];
  float* ws = (float*)d_ws;
  float* out = (float*)d_out;

  // zero stats + featsum
  zero_k<<<19, 256, 0, stream>>>(ws + OFF_STATB, 4864);

  conv_tile<3,16,256,256, 8,16, 8,4, 512, 0, 1><<<128, 512, 0, stream>>>(
      img, c0w, c0b, nullptr, nullptr, nullptr, ws + OFF_Y0, ws + OFF_STAT0);
  conv_tile<16,32,128,128, 2,32, 4,4, 256, 1, 16384><<<256, 256, 0, stream>>>(
      ws + OFF_Y0, c1w, c1b, ws + OFF_STAT0, n0g, n0b, ws + OFF_Y1, ws + OFF_STAT1);
  conv_tile<32,64,64,64, 2,32, 4,2, 256, 1, 4096><<<256, 256, 0, stream>>>(
      ws + OFF_Y1, c2w, c2b, ws + OFF_STAT1, n1g, n1b, ws + OFF_Y2, ws + OFF_STAT2);
  conv_tile<64,128,32,32, 2,32, 2,2, 256, 1, 1024><<<256, 256, 0, stream>>>(
      ws + OFF_Y2, c3w, c3b, ws + OFF_STAT2, n2g, n2b, ws + OFF_Y3, ws + OFF_STAT3);
  conv_tile<128,128,16,16, 2,16, 1,1, 256, 2, 256><<<256, 256, 0, stream>>>(
      ws + OFF_Y3, c4w, c4b, ws + OFF_STAT3, n3g, n3b, nullptr, ws + OFF_FEATS);

  head_kernel<<<1, 256, 0, stream>>>(
      ws + OFF_FEATS, cls0_w, cls0_b, cls1_w, cls1_b, ws + OFF_WGT);
  tmat_kernel<<<dim3(5, 300), 256, 0, stream>>>(luts, w_layers, ws + OFF_T);
  lutc_kernel<<<141*8, 256, 0, stream>>>(
      ws + OFF_T, ws + OFF_WGT, s_layers, (uint2*)(ws + OFF_LUTC));
  lut_expand_kernel<<<141*8, 256, 0, stream>>>(
      (const uint2*)(ws + OFF_LUTC), (uint4*)(ws + OFF_LUT64));
  trilin_kernel<<<900*8, 256, 0, stream>>>(
      img_org, (const uint4*)(ws + OFF_LUT64), out);
}

// Round 5
// 296.651 us; speedup vs baseline: 3.1958x; 1.0061x over previous
//
#include <hip/hip_runtime.h>
#include <hip/hip_fp16.h>

// ---------------- workspace layout (float offsets) ----------------
// Expanded LUT (written late, by lut_expand) overlaps Y0..Y3 (dead by then).
constexpr size_t OFF_Y0    = 0;         // 8*16*128*128 = 2097152
constexpr size_t OFF_Y1    = 2097152;   // 8*32*64*64   = 1048576
constexpr size_t OFF_Y2    = 3145728;   // 8*64*32*32   = 524288
constexpr size_t OFF_Y3    = 3670016;   // 8*128*16*16  = 262144 (ends 3932160)
constexpr size_t OFF_LUT64 = 0;         // 8*35937*16 floats = 4599936 (64B entries)
constexpr size_t OFF_T     = 4599936;   // 300*1089 = 326700 (ends 4926636)
constexpr size_t OFF_STATB = 4926640;
constexpr size_t OFF_STAT0 = OFF_STATB + 0;     // 8*16*2  = 256
constexpr size_t OFF_STAT1 = OFF_STATB + 256;   // 8*32*2  = 512
constexpr size_t OFF_STAT2 = OFF_STATB + 768;   // 8*64*2  = 1024
constexpr size_t OFF_STAT3 = OFF_STATB + 1792;  // 8*128*2 = 2048
constexpr size_t OFF_FEATS = OFF_STATB + 3840;  // 8*128   = 1024
constexpr size_t OFF_WGT   = OFF_STATB + 4864;  // 8*20 -> 256
constexpr size_t OFF_LUTC  = 4931760;   // compact fp16 LUT: 8*35937*2 = 574992
// total = 5506752 floats ~= 22.0 MB

__global__ __launch_bounds__(256) void zero_k(float* __restrict__ p, int n) {
  int i = blockIdx.x*256 + threadIdx.x;
  if (i < n) p[i] = 0.f;
}

// ---------------- unified tiled conv: stride-2 3x3 + lrelu (+stats / +mean) ----------------
template<int CIN, int COUT, int HIN, int WIN, int TH, int OCG, int PX, int OCT,
         int BLK, int MODE, int NPXPREV>
__global__ __launch_bounds__(BLK) void conv_tile(
    const float* __restrict__ xin, const float* __restrict__ wgt,
    const float* __restrict__ bias, const float* __restrict__ stat_in,
    const float* __restrict__ gam, const float* __restrict__ bet,
    float* __restrict__ yout, float* __restrict__ stat_out)
{
  constexpr int HOUT = HIN/2, WOUT = WIN/2;
  constexpr int SEG  = WOUT + 4;
  constexpr int XROW = 2*SEG;
  constexpr int XPI  = (2*TH+1)*XROW;
  constexpr int NT   = HOUT/TH;
  constexpr int NSTRIP_B = TH*WOUT/PX;
  constexpr int GPT  = OCG/OCT;
  static_assert(BLK == NSTRIP_B*GPT, "thread mapping mismatch");
  constexpr int R = NSTRIP_B < 64 ? NSTRIP_B : 64;

  __shared__ __align__(16) float xs[CIN*XPI];
  __shared__ float s_sc[CIN], s_sf[CIN];

  const int tid = threadIdx.x;
  const int lin = blockIdx.x;
  const int b = lin & 7;
  const int r2 = lin >> 3;
  const int tile = r2 % NT;
  const int ocb  = r2 / NT;

  if constexpr (MODE == 0) {
    if (tid == 0) { s_sc[0] = 1.f/0.229f; s_sf[0] = -0.485f/0.229f; }
    else if (tid == 1) { s_sc[1] = 1.f/0.224f; s_sf[1] = -0.456f/0.224f; }
    else if (tid == 2) { s_sc[2] = 1.f/0.225f; s_sf[2] = -0.406f/0.225f; }
  } else {
    if (tid < CIN) {
      float S = stat_in[(b*CIN+tid)*2+0], Q = stat_in[(b*CIN+tid)*2+1];
      float mean = S*(1.0f/NPXPREV);
      float var  = Q*(1.0f/NPXPREV) - mean*mean;
      float rstd = rsqrtf(var + 1e-5f);
      float gg = gam[tid], bb = bet[tid];
      s_sc[tid] = gg*rstd;
      s_sf[tid] = bb - mean*gg*rstd;
    }
  }
  __syncthreads();

  const int iy0 = tile*(2*TH) - 1;
  const float* xb_g = xin + (size_t)b*CIN*HIN*WIN;
  for (int e = tid; e < CIN*(2*TH+1)*(WIN+2); e += BLK) {
    int ic  = e / ((2*TH+1)*(WIN+2));
    int rem = e - ic*((2*TH+1)*(WIN+2));
    int rr  = rem / (WIN+2);
    int cc  = rem - rr*(WIN+2);
    int iy = iy0 + rr, ix = cc - 1;
    float v = 0.f;
    if (iy >= 0 && iy < HIN && ix >= 0 && ix < WIN)
      v = s_sc[ic]*xb_g[ic*HIN*WIN + iy*WIN + ix] + s_sf[ic];
    int off = (ix & 1) ? (SEG + ((ix+1) >> 1)) : (ix >> 1);
    xs[ic*XPI + rr*XROW + off] = v;
  }
  __syncthreads();

  const int s  = tid % NSTRIP_B;
  const int g  = tid / NSTRIP_B;
  const int r  = s / (WOUT/PX);
  const int c0 = (s % (WOUT/PX)) * PX;
  const int oc0 = ocb*OCG + g*OCT;

  float acc[OCT][PX];
  #pragma unroll
  for (int k = 0; k < OCT; ++k) {
    float bb = bias[oc0+k];
    #pragma unroll
    for (int j = 0; j < PX; ++j) acc[k][j] = bb;
  }

  float wv[OCT][9];
  #pragma unroll
  for (int k = 0; k < OCT; ++k) {
    const float* wp = wgt + ((size_t)(oc0+k)*CIN)*9;
    #pragma unroll
    for (int t = 0; t < 9; ++t) wv[k][t] = wp[t];
  }

  for (int ic = 0; ic < CIN; ++ic) {
    float wn[OCT][9];
    if (ic + 1 < CIN) {
      #pragma unroll
      for (int k = 0; k < OCT; ++k) {
        const float* wp = wgt + ((size_t)(oc0+k)*CIN + ic + 1)*9;
        #pragma unroll
        for (int t = 0; t < 9; ++t) wn[k][t] = wp[t];
      }
    }
    const float* xb = xs + ic*XPI;
    #pragma unroll
    for (int ky = 0; ky < 3; ++ky) {
      const float* rowp = xb + (2*r+ky)*XROW;
      float eb[PX], ob[PX+1];
      if constexpr (PX == 8) {
        *(float4*)&eb[0] = *(const float4*)(rowp + c0);
        *(float4*)&eb[4] = *(const float4*)(rowp + c0 + 4);
        *(float4*)&ob[0] = *(const float4*)(rowp + SEG + c0);
        *(float4*)&ob[4] = *(const float4*)(rowp + SEG + c0 + 4);
        ob[8] = rowp[SEG + c0 + 8];
      } else if constexpr (PX == 4) {
        *(float4*)&eb[0] = *(const float4*)(rowp + c0);
        *(float4*)&ob[0] = *(const float4*)(rowp + SEG + c0);
        ob[4] = rowp[SEG + c0 + 4];
      } else if constexpr (PX == 2) {
        *(float2*)&eb[0] = *(const float2*)(rowp + c0);
        *(float2*)&ob[0] = *(const float2*)(rowp + SEG + c0);
        ob[2] = rowp[SEG + c0 + 2];
      } else {
        eb[0] = rowp[c0];
        ob[0] = rowp[SEG + c0];
        ob[1] = rowp[SEG + c0 + 1];
      }
      #pragma unroll
      for (int k = 0; k < OCT; ++k) {
        float w0 = wv[k][ky*3], w1 = wv[k][ky*3+1], w2 = wv[k][ky*3+2];
        #pragma unroll
        for (int j = 0; j < PX; ++j)
          acc[k][j] += w0*ob[j] + w1*eb[j] + w2*ob[j+1];
      }
    }
    if (ic + 1 < CIN) {
      #pragma unroll
      for (int k = 0; k < OCT; ++k)
        #pragma unroll
        for (int t = 0; t < 9; ++t) wv[k][t] = wn[k][t];
    }
  }

  const int oy = tile*TH + r;
  if constexpr (MODE != 2) {
    float lsum[OCT], lsq[OCT];
    #pragma unroll
    for (int k = 0; k < OCT; ++k) {
      float ov[PX];
      float ls = 0.f, lq = 0.f;
      #pragma unroll
      for (int j = 0; j < PX; ++j) {
        float a = acc[k][j];
        a = a >= 0.f ? a : 0.2f*a;
        ov[j] = a; ls += a; lq += a*a;
      }
      lsum[k] = ls; lsq[k] = lq;
      float* yp = yout + (((size_t)b*COUT + oc0 + k)*HOUT + oy)*WOUT + c0;
      if constexpr (PX == 8) {
        *(float4*)yp = *(float4*)&ov[0];
        *(float4*)(yp+4) = *(float4*)&ov[4];
      } else if constexpr (PX == 4) {
        *(float4*)yp = *(float4*)&ov[0];
      } else if constexpr (PX == 2) {
        *(float2*)yp = *(float2*)&ov[0];
      } else {
        *yp = ov[0];
      }
    }
    #pragma unroll
    for (int k = 0; k < OCT; ++k) {
      #pragma unroll
      for (int off = R/2; off > 0; off >>= 1) {
        lsum[k] += __shfl_down(lsum[k], off);
        lsq[k]  += __shfl_down(lsq[k],  off);
      }
    }
    if ((tid & (R-1)) == 0) {
      #pragma unroll
      for (int k = 0; k < OCT; ++k) {
        atomicAdd(&stat_out[(b*COUT + oc0 + k)*2 + 0], lsum[k]);
        atomicAdd(&stat_out[(b*COUT + oc0 + k)*2 + 1], lsq[k]);
      }
    }
  } else {
    float a = acc[0][0];
    a = a >= 0.f ? a : 0.2f*a;
    #pragma unroll
    for (int off = R/2; off > 0; off >>= 1) a += __shfl_down(a, off);
    if ((tid & (R-1)) == 0) atomicAdd(&stat_out[b*COUT + oc0], a);
  }
}

// ---------------- classifier head (featsum -> weights) ----------------
__global__ __launch_bounds__(256) void head_kernel(
    const float* __restrict__ featsum, const float* __restrict__ w0, const float* __restrict__ b0,
    const float* __restrict__ w1, const float* __restrict__ b1, float* __restrict__ wout)
{
  __shared__ float sh_h[8*128];
  const int tid = threadIdx.x;
  for (int i = tid; i < 8*128; i += 256) {
    int b = i >> 7, t = i & 127;
    const float* f = featsum + b*128;
    const float* w = w0 + t*128;
    float a = 0.f;
    for (int k = 0; k < 128; ++k) a += f[k]*w[k];
    a = b0[t] + a*(1.0f/64.0f);
    float c = fminf(fmaxf(a + 3.f, 0.f), 6.f);
    sh_h[i] = a * c * (1.f/6.f);
  }
  __syncthreads();
  for (int i = tid; i < 8*20; i += 256) {
    int b = i/20, n = i - b*20;
    const float* h = sh_h + b*128;
    const float* w = w1 + n*128;
    float a = b1[n];
    for (int k = 0; k < 128; ++k) a += h[k]*w[k];
    wout[b*20 + n] = a;
  }
}

// ---------------- T = luts(300x20) @ w_layers(20x1089) ----------------
__global__ __launch_bounds__(256) void tmat_kernel(
    const float* __restrict__ luts, const float* __restrict__ wl, float* __restrict__ T)
{
  int q = blockIdx.x*256 + threadIdx.x;
  int row = blockIdx.y;
  if (q >= 1089) return;
  float a = 0.f;
  #pragma unroll
  for (int w = 0; w < 20; ++w) a += luts[row*20 + w] * wl[w*1089 + q];
  T[row*1089 + q] = a;
}

// ---------------- pass1: compact fp16 LUT, one corner per entry (8B) ----------------
__global__ __launch_bounds__(256) void lutc_kernel(
    const float* __restrict__ T, const float* __restrict__ wgt,
    const float* __restrict__ slay, uint2* __restrict__ lutc)
{
  const int lin = blockIdx.x;
  const int bt = lin & 7;
  const int i = (lin >> 3)*256 + threadIdx.x;
  if (i >= 35937) return;
  int bi = i / 1089, rem = i - bi*1089, gi = rem / 33, ri = rem - gi*33;
  float w[20];
  #pragma unroll
  for (int n = 0; n < 20; ++n) w[n] = wgt[bt*20 + n];

  const int qv[3]  = { bi*33 + gi, bi*33 + ri, gi*33 + ri };
  const int d0v[3] = { ri, gi, bi };
  float outv[3];
  #pragma unroll
  for (int ch = 0; ch < 3; ++ch) {
    float val = 0.f;
    #pragma unroll
    for (int s = 0; s < 5; ++s) {
      float t = 0.f;
      #pragma unroll
      for (int n = 0; n < 20; ++n)
        t += w[n] * T[(s*60 + n*3 + ch)*1089 + qv[ch]];
      val += slay[d0v[ch]*5 + s] * t;
    }
    outv[ch] = val;
  }
  union { __half2 h2; unsigned u; } p0, p1;
  p0.h2 = __floats2half2_rn(outv[0], outv[1]);
  p1.h2 = __floats2half2_rn(outv[2], 0.f);
  lutc[(size_t)bt*35937 + i] = make_uint2(p0.u, p1.u);
}

// ---------------- pass2: expand to 64B entries holding all 8 corners ----------------
__global__ __launch_bounds__(256) void lut_expand_kernel(
    const uint2* __restrict__ lutc, uint4* __restrict__ lut64)
{
  const int lin = blockIdx.x;
  const int bt = lin & 7;
  const int i = (lin >> 3)*256 + threadIdx.x;
  if (i >= 35937) return;
  int bi = i / 1089, rem = i - bi*1089, gi = rem / 33, ri = rem - gi*33;
  const int b1 = bi < 32 ? bi+1 : 32, g1 = gi < 32 ? gi+1 : 32, r1 = ri < 32 ? ri+1 : 32;
  const uint2* base = lutc + (size_t)bt*35937;
  union { unsigned short h[32]; uint4 q[4]; } u;
  #pragma unroll
  for (int t = 24; t < 32; ++t) u.h[t] = 0;
  const int bsel[2] = { bi, b1 }, gsel[2] = { gi, g1 }, rsel[2] = { ri, r1 };
  #pragma unroll
  for (int db = 0; db < 2; ++db)
    #pragma unroll
    for (int dg = 0; dg < 2; ++dg)
      #pragma unroll
      for (int dr = 0; dr < 2; ++dr) {
        const int idx = db*4 + dg*2 + dr;
        uint2 s = base[(bsel[db]*33 + gsel[dg])*33 + rsel[dr]];
        u.h[idx*3+0] = (unsigned short)(s.x & 0xffff);
        u.h[idx*3+1] = (unsigned short)(s.x >> 16);
        u.h[idx*3+2] = (unsigned short)(s.y & 0xffff);
      }
  uint4* dst = lut64 + ((size_t)bt*35937 + i)*4;
  dst[0] = u.q[0]; dst[1] = u.q[1]; dst[2] = u.q[2]; dst[3] = u.q[3];
}

// ---------------- trilinear apply + residual: 1 line/px, 12 gathers in flight ----------------
__global__ __launch_bounds__(256) void trilin_kernel(
    const float* __restrict__ img, const uint4* __restrict__ lut, float* __restrict__ out)
{
  constexpr int NPX = 720*1280;
  const int lin = blockIdx.x;
  const int bt = lin & 7;
  const int v = (lin >> 3)*256 + threadIdx.x;   // < NPX/4 exactly (900*256)
  const float* ib = img + (size_t)bt*3*NPX;
  float4 r4 = *((const float4*)ib + v);
  float4 g4 = *((const float4*)(ib + NPX) + v);
  float4 b4 = *((const float4*)(ib + 2*NPX) + v);
  const uint4* L = lut + (size_t)bt*35937*4;
  const float invbin = 32.0f/1.000001f;

  // phase 1: bases + fracs for all 4 px
  int base[4];
  float fr[4], fg[4], fb[4];
  #pragma unroll
  for (int j = 0; j < 4; ++j) {
    float r = ((float*)&r4)[j], g = ((float*)&g4)[j], b = ((float*)&b4)[j];
    float pr = r*invbin, pg = g*invbin, pb = b*invbin;
    int ri = (int)pr; ri = ri > 31 ? 31 : ri; ri = ri < 0 ? 0 : ri;
    int gi = (int)pg; gi = gi > 31 ? 31 : gi; gi = gi < 0 ? 0 : gi;
    int bi = (int)pb; bi = bi > 31 ? 31 : bi; bi = bi < 0 ? 0 : bi;
    fr[j] = pr - ri; fg[j] = pg - gi; fb[j] = pb - bi;
    base[j] = (bi*33 + gi)*33 + ri;
  }
  // phase 2: issue all 12 gathers (statically indexed -> stays in VGPRs)
  uint4 q0[4], q1[4], q2[4];
  #pragma unroll
  for (int j = 0; j < 4; ++j) {
    const uint4* e = L + (size_t)base[j]*4;
    q0[j] = e[0]; q1[j] = e[1]; q2[j] = e[2];
  }
  // phase 3: weighted sums
  float4 ro, go, bo;
  float* rp = (float*)&ro; float* gp = (float*)&go; float* bp = (float*)&bo;
  #pragma unroll
  for (int j = 0; j < 4; ++j) {
    union { uint4 q[3]; __half h[24]; } u;
    u.q[0] = q0[j]; u.q[1] = q1[j]; u.q[2] = q2[j];
    float wr1 = fr[j], wr0 = 1.f-fr[j];
    float wg1 = fg[j], wg0 = 1.f-fg[j];
    float wb1 = fb[j], wb0 = 1.f-fb[j];
    float w00 = wb0*wg0, w01 = wb0*wg1, w10 = wb1*wg0, w11 = wb1*wg1;
    float wt[8] = { w00*wr0, w00*wr1, w01*wr0, w01*wr1,
                    w10*wr0, w10*wr1, w11*wr0, w11*wr1 };
    float rr = 0.f, gg = 0.f, bb2 = 0.f;
    #pragma unroll
    for (int idx = 0; idx < 8; ++idx) {
      float wv = wt[idx];
      rr  += wv * __half2float(u.h[idx*3+0]);
      gg  += wv * __half2float(u.h[idx*3+1]);
      bb2 += wv * __half2float(u.h[idx*3+2]);
    }
    rp[j] = rr + ((float*)&r4)[j];
    gp[j] = gg + ((float*)&g4)[j];
    bp[j] = bb2 + ((float*)&b4)[j];
  }
  float* ob = out + (size_t)bt*3*NPX;
  *((float4*)ob + v) = ro;
  *((float4*)(ob + NPX) + v) = go;
  *((float4*)(ob + 2*NPX) + v) = bo;
}

// ---------------- launcher ----------------
extern "C" void kernel_launch(void* const* d_in, const int* in_sizes, int n_in,
                              void* d_out, int out_size, void* d_ws, size_t ws_size,
                              hipStream_t stream) {
  const float* img     = (const float*)d_in[0];
  const float* img_org = (const float*)d_in[1];
  const float* c0w = (const float*)d_in[2];  const float* c0b = (const float*)d_in[3];
  const float* c1w = (const float*)d_in[4];  const float* c1b = (const float*)d_in[5];
  const float* c2w = (const float*)d_in[6];  const float* c2b = (const float*)d_in[7];
  const float* c3w = (const float*)d_in[8];  const float* c3b = (const float*)d_in[9];
  const float* c4w = (const float*)d_in[10]; const float* c4b = (const float*)d_in[11];
  const float* n0g = (const float*)d_in[12]; const float* n0b = (const float*)d_in[13];
  const float* n1g = (const float*)d_in[14]; const float* n1b = (const float*)d_in[15];
  const float* n2g = (const float*)d_in[16]; const float* n2b = (const float*)d_in[17];
  const float* n3g = (const float*)d_in[18]; const float* n3b = (const float*)d_in[19];
  const float* cls0_w = (const float*)d_in[20]; const float* cls0_b = (const float*)d_in[21];
  const float* cls1_w = (const float*)d_in[22]; const float* cls1_b = (const float*)d_in[23];
  const float* s_layers = (const float*)d_in[24];
  const float* w_layers = (const float*)d_in[25];
  const float* luts     = (const float*)d_in[26];
  float* ws = (float*)d_ws;
  float* out = (float*)d_out;

  // zero stats + featsum
  zero_k<<<19, 256, 0, stream>>>(ws + OFF_STATB, 4864);

  // conv0: 3->16, 256->128. TH=4 (28.5 KB LDS, 256 blocks)
  conv_tile<3,16,256,256, 4,16, 8,4, 256, 0, 1><<<256, 256, 0, stream>>>(
      img, c0w, c0b, nullptr, nullptr, nullptr, ws + OFF_Y0, ws + OFF_STAT0);
  conv_tile<16,32,128,128, 2,32, 4,4, 256, 1, 16384><<<256, 256, 0, stream>>>(
      ws + OFF_Y0, c1w, c1b, ws + OFF_STAT0, n0g, n0b, ws + OFF_Y1, ws + OFF_STAT1);
  conv_tile<32,64,64,64, 2,32, 4,2, 256, 1, 4096><<<256, 256, 0, stream>>>(
      ws + OFF_Y1, c2w, c2b, ws + OFF_STAT1, n1g, n1b, ws + OFF_Y2, ws + OFF_STAT2);
  conv_tile<64,128,32,32, 2,32, 2,2, 256, 1, 1024><<<256, 256, 0, stream>>>(
      ws + OFF_Y2, c3w, c3b, ws + OFF_STAT2, n2g, n2b, ws + OFF_Y3, ws + OFF_STAT3);
  conv_tile<128,128,16,16, 2,16, 1,1, 256, 2, 256><<<256, 256, 0, stream>>>(
      ws + OFF_Y3, c4w, c4b, ws + OFF_STAT3, n3g, n3b, nullptr, ws + OFF_FEATS);

  head_kernel<<<1, 256, 0, stream>>>(
      ws + OFF_FEATS, cls0_w, cls0_b, cls1_w, cls1_b, ws + OFF_WGT);
  tmat_kernel<<<dim3(5, 300), 256, 0, stream>>>(luts, w_layers, ws + OFF_T);
  lutc_kernel<<<141*8, 256, 0, stream>>>(
      ws + OFF_T, ws + OFF_WGT, s_layers, (uint2*)(ws + OFF_LUTC));
  lut_expand_kernel<<<141*8, 256, 0, stream>>>(
      (const uint2*)(ws + OFF_LUTC), (uint4*)(ws + OFF_LUT64));
  trilin_kernel<<<900*8, 256, 0, stream>>>(
      img_org, (const uint4*)(ws + OFF_LUT64), out);
}